// Round 9
// baseline (691.011 us; speedup 1.0000x reference)
//
#include <hip/hip_runtime.h>
#include <hip/hip_bf16.h>
#include <math.h>

// Problem constants (match reference)
#define T_TOK 1024
#define HID   2048
#define NEXP  64
#define IDIM  1024
#define ISH   2048      // IS = I * N_SHARED
#define TOPK  8

typedef float  f32x4  __attribute__((ext_vector_type(4)));
typedef __bf16 bf16x8 __attribute__((ext_vector_type(8)));

#define BM  128
#define BN_ 64
#define BK  32

// Barrier that does NOT drain vmcnt (waits own DS ops only).
#define BARRIER_NODRAIN() asm volatile("s_waitcnt lgkmcnt(0)\n\ts_barrier" ::: "memory")

__device__ __forceinline__ bf16x8 cvt8(f32x4 a, f32x4 b) {
  bf16x8 v;
  v[0]=(__bf16)a[0]; v[1]=(__bf16)a[1]; v[2]=(__bf16)a[2]; v[3]=(__bf16)a[3];
  v[4]=(__bf16)b[0]; v[5]=(__bf16)b[1]; v[6]=(__bf16)b[2]; v[7]=(__bf16)b[3];
  return v;
}

// ---------------- init: zero expert counts ----------------
__global__ void init_kernel(int* counts) {
  if (threadIdx.x < NEXP) counts[threadIdx.x] = 0;
}

// ---------------- x (f32) -> x_bf16 ----------------
__global__ void xcast_kernel(const float* __restrict__ x, __bf16* __restrict__ xb) {
  long i = ((long)blockIdx.x * 256 + threadIdx.x) * 8;
  f32x4 a = *(const f32x4*)(x + i);
  f32x4 b = *(const f32x4*)(x + i + 4);
  *(bf16x8*)(xb + i) = cvt8(a, b);
}

// ---------------- router: logits + sigmoid + grouped top-k (f32) ----------------
__global__ __launch_bounds__(256)
void router_kernel(const float* __restrict__ x, const float* __restrict__ gw,
                   const float* __restrict__ eb,
                   int* __restrict__ ids, float* __restrict__ wts,
                   int* __restrict__ counts)
{
  __shared__ __align__(16) float xs[HID];
  __shared__ float red[256];
  __shared__ float sc[NEXP], sb[NEXP];
  const int t = blockIdx.x, tid = threadIdx.x;

  const f32x4* xsrc = (const f32x4*)(x + (long)t * HID);
  f32x4* xd = (f32x4*)xs;
  xd[tid]       = xsrc[tid];
  xd[tid + 256] = xsrc[tid + 256];
  __syncthreads();

  const int e = tid & 63, part = tid >> 6;
  const f32x4* wrow = (const f32x4*)(gw + (long)e * HID + part * 512);
  const f32x4* xrow = (const f32x4*)(xs + part * 512);
  float s = 0.f;
  #pragma unroll 4
  for (int j = 0; j < 128; ++j) {
    f32x4 wv = wrow[j], xv = xrow[j];
    s += wv[0]*xv[0] + wv[1]*xv[1] + wv[2]*xv[2] + wv[3]*xv[3];
  }
  red[tid] = s;
  __syncthreads();
  if (part == 0) {
    float logit = red[e] + red[e+64] + red[e+128] + red[e+192];
    float sig = 1.f / (1.f + expf(-logit));   // accurate exp: selection must match f32 ref
    sc[e] = sig; sb[e] = sig + eb[e];
  }
  __syncthreads();

  if (tid == 0) {
    float gsc[8];
    for (int g = 0; g < 8; ++g) {
      float m1 = -1e30f, m2 = -1e30f;
      for (int j = 0; j < 8; ++j) {
        float v = sb[g*8 + j];
        if (v > m1) { m2 = m1; m1 = v; } else if (v > m2) m2 = v;
      }
      gsc[g] = m1 + m2;
    }
    unsigned gmask = 0;
    for (int it = 0; it < 4; ++it) {
      int best = 0; float bv = -1e30f;
      for (int g = 0; g < 8; ++g)
        if (!((gmask >> g) & 1) && gsc[g] > bv) { bv = gsc[g]; best = g; }
      gmask |= 1u << best;
    }
    unsigned long long taken = 0;
    int id8[8]; float wsum = 0.f;
    for (int it = 0; it < 8; ++it) {
      int best = 0; float bv = -1e30f;
      for (int e2 = 0; e2 < 64; ++e2) {
        if (!((gmask >> (e2 >> 3)) & 1)) continue;
        if ((taken >> e2) & 1) continue;
        float v = sb[e2];
        if (v > bv) { bv = v; best = e2; }
      }
      taken |= 1ull << best;
      id8[it] = best; wsum += sc[best];
    }
    float inv = 2.5f / wsum;   // fold ROUTED_SCALE into weights
    for (int k = 0; k < 8; ++k) {
      ids[t*8 + k] = id8[k];
      wts[t*8 + k] = sc[id8[k]] * inv;
      atomicAdd(&counts[id8[k]], 1);
    }
  }
}

// ---------------- prefix scan + (expert, mt) pair worklist (BM=128 chunks) ----
__global__ void scan_kernel(const int* __restrict__ counts,
                            int* __restrict__ seg_off, int* __restrict__ cursors,
                            int* __restrict__ pair_e, int* __restrict__ pair_mt,
                            int* __restrict__ npairs) {
  if (threadIdx.x == 0) {
    int off = 0, np = 0;
    for (int e = 0; e < NEXP; ++e) {
      seg_off[e] = off; cursors[e] = off;
      int c = counts[e]; off += c;
      for (int m = 0; m * BM < c; ++m) { pair_e[np] = e; pair_mt[np] = m; ++np; }
    }
    npairs[0] = np;
  }
}

// ---------------- scatter (t, w) into per-expert segments ----------------
__global__ void scatter_kernel(const int* __restrict__ ids, const float* __restrict__ wts,
                               int* __restrict__ cursors,
                               int* __restrict__ tok_list, float* __restrict__ wgt_list,
                               int* __restrict__ pos_of) {
  int idx = blockIdx.x * 256 + threadIdx.x;
  if (idx >= T_TOK * TOPK) return;
  int t = idx >> 3;
  int e = ids[idx];
  int pos = atomicAdd(&cursors[e], 1);
  tok_list[pos] = t;
  wgt_list[pos] = wts[idx];
  pos_of[idx] = pos;
}

// ---------------- unified DMA streaming GEMM (traffic-minimized) ----------------
// NS=2: fused gate+up (two B streams), epilogue h = w*silu(g)*u -> bf16.
// NS=1: plain GEMM; EPI 0 = bf16 store, EPI 2 = f32 store.
// A (bf16) + B (f32) DMA-staged (global_load_lds 16B, linear dest,
// inverse-XOR-swizzled source, swizzled read). BK=32, 3-deep rotation,
// counted vmcnt (6 instrs/stage NS=2, 4 NS=1), one no-drain barrier/step.
// XCD co-location: 1-D grid, wgid -> (xcd=wgid&7, nt, pair=q*8+xcd) so all
// nt-blocks of a pair share one XCD's L2 -> A-tile fetched once per pair.
template<int NS, int EPI, bool ROUTED, bool GATHER>
__global__ __launch_bounds__(256, 2)
void gemm_x(const __bf16* __restrict__ A, const float* __restrict__ Bg0,
            const float* __restrict__ Bu0, long strideBe, int ldB, int K,
            void* __restrict__ Cout, int ldc, int NTB,
            const int* __restrict__ pair_e, const int* __restrict__ pair_mt,
            const int* __restrict__ npairs,
            const int* __restrict__ seg_off, const int* __restrict__ seg_cnt,
            const int* __restrict__ tok_list, const float* __restrict__ wgt_list,
            int Mfull)
{
  constexpr int BUFSZ = (1 + NS) * 8192;
  __shared__ __align__(16) char smem[3 * BUFSZ];
  __shared__ float sWs[BM];
  const int tid = threadIdx.x, lane = tid & 63, wv = tid >> 6;
  const int c15 = lane & 15, hi = lane >> 4;

  const int wgid = blockIdx.x;
  const int nt   = (wgid >> 3) % NTB;
  const int p    = (wgid / (8 * NTB)) * 8 + (wgid & 7);

  int e, mt0, soff, cnt;
  if (ROUTED) {
    if (p >= npairs[0]) return;
    e = pair_e[p]; mt0 = pair_mt[p]; soff = seg_off[e]; cnt = seg_cnt[e];
  } else {
    if (p >= Mfull / BM) return;
    e = 0; mt0 = p; soff = 0; cnt = Mfull;
  }
  const int rem = cnt - mt0 * BM;
  if (rem <= 0) return;

  // staging sources (content pre-XOR-swizzled; LDS dest stays linear)
  const __bf16* srcA[2];
  #pragma unroll
  for (int i = 0; i < 2; ++i) {
    int ia  = wv * 2 + i;
    int row = ia * 16 + (lane >> 2);
    int kq  = (lane & 3) ^ (row & 3);
    int rr  = (row < rem) ? row : (rem - 1);
    int idx = soff + mt0 * BM + rr;
    long arow = GATHER ? (long)tok_list[idx] : (long)idx;
    srcA[i] = A + arow * (long)K + kq * 8;
  }
  const float* srcB0[2];
  const float* srcB1[2];
  {
    const float* Bb0 = Bg0 + (long)e * strideBe;
    const float* Bb1 = Bu0 + (long)e * strideBe;
    #pragma unroll
    for (int i = 0; i < 2; ++i) {
      int ib  = wv * 2 + i;
      int col = ib * 8 + (lane >> 3);
      int kq  = (lane & 7) ^ (col & 7);
      long boff = (long)(nt * BN_ + col) * ldB + kq * 4;
      srcB0[i] = Bb0 + boff;
      srcB1[i] = Bb1 + boff;
    }
  }

#define STAGE(b, kk) { \
  char* base_ = smem + (b) * BUFSZ; \
  _Pragma("unroll") \
  for (int i = 0; i < 2; ++i) \
    __builtin_amdgcn_global_load_lds((const __attribute__((address_space(1))) void*)(srcA[i] + (kk)), \
        (__attribute__((address_space(3))) void*)(base_ + (wv * 2 + i) * 1024), 16, 0, 0); \
  _Pragma("unroll") \
  for (int i = 0; i < 2; ++i) \
    __builtin_amdgcn_global_load_lds((const __attribute__((address_space(1))) void*)(srcB0[i] + (kk)), \
        (__attribute__((address_space(3))) void*)(base_ + 8192 + (wv * 2 + i) * 1024), 16, 0, 0); \
  if constexpr (NS == 2) { \
    _Pragma("unroll") \
    for (int i = 0; i < 2; ++i) \
      __builtin_amdgcn_global_load_lds((const __attribute__((address_space(1))) void*)(srcB1[i] + (kk)), \
          (__attribute__((address_space(3))) void*)(base_ + 16384 + (wv * 2 + i) * 1024), 16, 0, 0); \
  } }

  f32x4 accg[8] = {};
  f32x4 accu[8] = {};

#define COMPUTE(b) { \
  const char* base_ = smem + (b) * BUFSZ; \
  const int cb = ((wv * 2 + (c15 >> 3)) << 10) + ((c15 & 7) << 7); \
  const int cx = c15 & 7; \
  const char* Bl0 = base_ + 8192; \
  f32x4 g0 = *(const f32x4*)(Bl0 + cb + ((((hi * 2)    ) ^ cx) << 4)); \
  f32x4 g1 = *(const f32x4*)(Bl0 + cb + ((((hi * 2) + 1) ^ cx) << 4)); \
  bf16x8 bg = cvt8(g0, g1); \
  bf16x8 bu = bg; \
  if constexpr (NS == 2) { \
    const char* Bl1 = base_ + 16384; \
    f32x4 u0 = *(const f32x4*)(Bl1 + cb + ((((hi * 2)    ) ^ cx) << 4)); \
    f32x4 u1 = *(const f32x4*)(Bl1 + cb + ((((hi * 2) + 1) ^ cx) << 4)); \
    bu = cvt8(u0, u1); \
  } \
  _Pragma("unroll") \
  for (int m = 0; m < 8; ++m) { \
    bf16x8 af = *(const bf16x8*)(base_ + (m << 10) + (((c15 << 2) + (hi ^ (c15 & 3))) << 4)); \
    accg[m] = __builtin_amdgcn_mfma_f32_16x16x32_bf16(af, bg, accg[m], 0, 0, 0); \
    if constexpr (NS == 2) \
      accu[m] = __builtin_amdgcn_mfma_f32_16x16x32_bf16(af, bu, accu[m], 0, 0, 0); \
  } }

  const int NT = K / BK;
  STAGE(0, 0);
  STAGE(1, BK);
  for (int t = 0; t < NT; ++t) {
    if constexpr (NS == 2) asm volatile("s_waitcnt vmcnt(6)" ::: "memory");
    else                   asm volatile("s_waitcnt vmcnt(4)" ::: "memory");
    BARRIER_NODRAIN();                               // everyone's stage(t) landed, buf (t+2)%3 free
    const int kk = (t + 2 < NT) ? (t + 2) * BK : 0;  // tail: dummy re-stage keeps vmcnt invariant
    STAGE((t + 2) % 3, kk);
    COMPUTE(t % 3);
  }
#undef STAGE
#undef COMPUTE

  if constexpr (NS == 2) {
    if (tid < BM) {
      int rr = (tid < rem) ? tid : (rem - 1);
      sWs[tid] = ROUTED ? wgt_list[soff + mt0 * BM + rr] : 1.f;
    }
  }
  asm volatile("s_waitcnt vmcnt(0)" ::: "memory");   // drain dummy stages
  __syncthreads();

  if constexpr (EPI == 0) {
    __bf16* Cs = (__bf16*)smem;                      // reuse buf0 as transpose scratch
    #pragma unroll
    for (int m = 0; m < 8; ++m) {
      #pragma unroll
      for (int r = 0; r < 4; ++r) {
        int row = m * 16 + hi * 4 + r;
        float v;
        if constexpr (NS == 2) {
          float g = accg[m][r], u = accu[m][r];
          v = sWs[row] * g * u / (1.f + __expf(-g));
        } else {
          v = accg[m][r];
        }
        Cs[row * 64 + wv * 16 + c15] = (__bf16)v;
      }
    }
    __syncthreads();
    __bf16* Cb = (__bf16*)Cout;
    #pragma unroll
    for (int p2 = 0; p2 < 4; ++p2) {
      int row = p2 * 32 + (tid >> 3);
      if (row < rem)
        *(bf16x8*)(Cb + (long)(soff + mt0 * BM + row) * ldc + nt * BN_ + (tid & 7) * 8) =
            *(const bf16x8*)&Cs[row * 64 + (tid & 7) * 8];
    }
  } else {
    float* O = (float*)Cout;
    const int col = nt * BN_ + wv * 16 + c15;
    #pragma unroll
    for (int m = 0; m < 8; ++m) {
      #pragma unroll
      for (int r = 0; r < 4; ++r) {
        int row = m * 16 + hi * 4 + r;
        if (row < rem)
          O[(long)(mt0 * BM + row) * ldc + col] = accg[m][r];
      }
    }
  }
}

// ---------------- combine: out[t] += sum_k y[pos(t,k)] ----------------
__global__ __launch_bounds__(256)
void combine_kernel(const __bf16* __restrict__ y, const int* __restrict__ pos_of,
                    float* __restrict__ out) {
  const int t = blockIdx.x;
  const int c0 = threadIdx.x * 8;
  float* orow = out + (long)t * HID + c0;
  f32x4 s0 = *(const f32x4*)orow;
  f32x4 s1 = *(const f32x4*)(orow + 4);
  #pragma unroll
  for (int k = 0; k < TOPK; ++k) {
    int row = pos_of[t * TOPK + k];
    bf16x8 v = *(const bf16x8*)(y + (long)row * HID + c0);
    s0[0] += (float)v[0]; s0[1] += (float)v[1]; s0[2] += (float)v[2]; s0[3] += (float)v[3];
    s1[0] += (float)v[4]; s1[1] += (float)v[5]; s1[2] += (float)v[6]; s1[3] += (float)v[7];
  }
  *(f32x4*)orow = s0;
  *(f32x4*)(orow + 4) = s1;
}

// ---------------- launch ----------------
extern "C" void kernel_launch(void* const* d_in, const int* in_sizes, int n_in,
                              void* d_out, int out_size, void* d_ws, size_t ws_size,
                              hipStream_t stream) {
  const float* x      = (const float*)d_in[0];
  const float* gate_w = (const float*)d_in[1];
  const float* e_bias = (const float*)d_in[2];
  const float* w_gate = (const float*)d_in[3];
  const float* w_up   = (const float*)d_in[4];
  const float* w_down = (const float*)d_in[5];
  const float* sw_gu  = (const float*)d_in[6];
  const float* sw_d   = (const float*)d_in[7];
  float* out = (float*)d_out;
  char* ws = (char*)d_ws;

  size_t off = 0;
  __bf16* x_bf = (__bf16*)(ws + off);        off += (size_t)T_TOK * HID * 2;   // 4 MB
  int*    ids  = (int*)(ws + off);           off += T_TOK * TOPK * 4;
  float*  wts  = (float*)(ws + off);         off += T_TOK * TOPK * 4;
  int* counts  = (int*)(ws + off);           off += 256;
  int* segoff  = (int*)(ws + off);           off += 256;
  int* cursors = (int*)(ws + off);           off += 256;
  int* pair_e  = (int*)(ws + off);           off += 1024;
  int* pair_mt = (int*)(ws + off);           off += 1024;
  int* npairs  = (int*)(ws + off);           off += 256;
  int* tok_list = (int*)(ws + off);          off += T_TOK * TOPK * 4;
  float* wgt_list = (float*)(ws + off);      off += T_TOK * TOPK * 4;
  int* pos_of  = (int*)(ws + off);           off += T_TOK * TOPK * 4;
  off = (off + 255) & ~(size_t)255;
  __bf16* h_buf  = (__bf16*)(ws + off);      off += (size_t)T_TOK * TOPK * IDIM * 2; // 16 MB
  __bf16* hs_buf = (__bf16*)(ws + off);      off += (size_t)T_TOK * ISH * 2;         // 4 MB
  __bf16* y_buf  = (__bf16*)(ws + off);      off += (size_t)T_TOK * TOPK * HID * 2;  // 32 MB

  init_kernel<<<1, 64, 0, stream>>>(counts);
  xcast_kernel<<<(T_TOK * HID) / (256 * 8), 256, 0, stream>>>(x, x_bf);
  router_kernel<<<T_TOK, 256, 0, stream>>>(x, gate_w, e_bias, ids, wts, counts);
  scan_kernel<<<1, 64, 0, stream>>>(counts, segoff, cursors, pair_e, pair_mt, npairs);
  scatter_kernel<<<(T_TOK * TOPK + 255) / 256, 256, 0, stream>>>(
      ids, wts, cursors, tok_list, wgt_list, pos_of);

  // routed fused gate+up -> h (weight+silu in epilogue). NTB=16 nt-blocks/pair.
  gemm_x<2, 0, true, true><<<128 * 16, 256, 0, stream>>>(
      x_bf, w_gate, w_up, (long)IDIM * HID, HID, HID, h_buf, IDIM, 16,
      pair_e, pair_mt, npairs, segoff, counts, tok_list, wgt_list, 0);

  // shared fused gate+up -> hs. NTB=32, mt = 0..7.
  gemm_x<2, 0, false, false><<<8 * 32, 256, 0, stream>>>(
      x_bf, sw_gu, sw_gu + (size_t)ISH * HID, 0, HID, HID, hs_buf, ISH, 32,
      nullptr, nullptr, nullptr, nullptr, nullptr, nullptr, nullptr, T_TOK);

  // shared down: f32 stores into out (initializes all of d_out). NTB=32.
  gemm_x<1, 2, false, false><<<8 * 32, 256, 0, stream>>>(
      hs_buf, sw_d, sw_d, 0, ISH, ISH, out, HID, 32,
      nullptr, nullptr, nullptr, nullptr, nullptr, nullptr, nullptr, T_TOK);

  // routed down -> y rows (bf16, atomic-free, segment-ordered). NTB=32.
  gemm_x<1, 0, true, false><<<128 * 32, 256, 0, stream>>>(
      h_buf, w_down, w_down, (long)HID * IDIM, IDIM, IDIM, y_buf, HID, 32,
      pair_e, pair_mt, npairs, segoff, counts, tok_list, wgt_list, 0);

  // combine: out[t] += sum of this token's 8 y rows
  combine_kernel<<<T_TOK, 256, 0, stream>>>(y_buf, pos_of, out);
}